// Round 7
// baseline (186.957 us; speedup 1.0000x reference)
//
#include <hip/hip_runtime.h>
#include <math.h>

typedef _Float16 f16;
typedef _Float16 f16x8 __attribute__((ext_vector_type(8)));
typedef float f32x16 __attribute__((ext_vector_type(16)));

#define MFMA_ __builtin_amdgcn_mfma_f32_32x32x16_f16
#define SLOPE_ 0.2f

constexpr int kB = 64, kT = 512, kD = 8, kH = 128, kE = 96;
constexpr int kFG = 145, kTM = 510, kN = kB * kTM;   // 32640 = 1020*32

// k-permutation absorbed into weight images so next-layer B-fragments are the
// held C/D quads verbatim: pi(16c+8s+j) = 32(c>>1)+16(c&1)+8(j>>2)+4s+(j&3)
__device__ __forceinline__ int pif(int k) {
  if (k >= 128) return k;                     // g L0 yy region stays canonical
  int c = k >> 4, s = (k >> 3) & 1, j = k & 7;
  return ((c >> 1) << 5) | ((c & 1) << 4) | ((j >> 2) << 3) | (s << 2) | (j & 3);
}

// fragment-linear images: frag f = 64 lanes x 16 B contiguous.
__device__ __forceinline__ f16x8 gfrag(const f16* img, int f, int lane) {
  return *(const f16x8*)(img + f*512 + lane*8);
}

// ========= weight pre-convert: f32 row-major -> f16 fragment-linear =========
template<int NF, int SK, int PERM>
__device__ __forceinline__ void cvt_img(const float* __restrict__ src,
                                        f16* __restrict__ dst, int nd,
                                        int t0, int stride) {
  const int per_d = NF * 512;
  for (int e = t0; e < nd * per_d; e += stride) {
    int dd = e / per_d, r = e - dd * per_d;
    int f = r >> 9, l = (r >> 3) & 63, j = r & 7;
    int c = f >> 2, t = f & 3;
    int row = t*32 + (l & 31);
    int col = c*16 + ((l >> 5) << 3) + j;
    if (PERM) col = pif(col);
    dst[e] = (f16)src[((size_t)dd*kH + row)*SK + col];
  }
}

__global__ __launch_bounds__(256) void cvt_kernel(
    const float* __restrict__ gW0, const float* __restrict__ gW1,
    const float* __restrict__ gW2,
    const float* __restrict__ fcW0, const float* __restrict__ fcW1,
    const float* __restrict__ fcWf,
    f16* __restrict__ W0img, f16* __restrict__ W1img, f16* __restrict__ W2img,
    f16* __restrict__ fW0img, f16* __restrict__ fW1img, f16* __restrict__ fWfimg,
    float* __restrict__ w144buf, float* __restrict__ logdet)
{
  const int stride = gridDim.x * 256;
  const int t0 = blockIdx.x*256 + threadIdx.x;
  cvt_img<36, kFG, 1>(gW0, W0img, kD, t0, stride);
  cvt_img<32, kH , 1>(gW1, W1img, kD, t0, stride);
  cvt_img<32, kH , 1>(gW2, W2img, kD, t0, stride);
  cvt_img<24, kE , 0>(fcW0, fW0img, 1, t0, stride);
  cvt_img<32, kH , 1>(fcW1, fW1img, 1, t0, stride);
  cvt_img<32, kH , 1>(fcWf, fWfimg, 1, t0, stride);
  for (int i = t0; i < kD*kH; i += stride)
    w144buf[i] = gW0[(size_t)i*kFG + 144];
  if (t0 < kB) logdet[t0] = 0.f;
}

// ===== fc_mlp: emb(N,96) -> embh (block-chunked frag layout), 32-row blocks =
// 2 waves: wave = col-half (2 h-tiles each). acc = 32 AGPR.
__global__ __launch_bounds__(128, 4) void fc_kernel(
    const float* __restrict__ emb,
    const f16* __restrict__ fW0, const f16* __restrict__ fW1,
    const f16* __restrict__ fWf,
    const float* __restrict__ b0, const float* __restrict__ b1,
    const float* __restrict__ bf, f16* __restrict__ out)
{
  __shared__ f16 act[8][512];                  // P act exchange, 8 KB
  const int bx = blockIdx.x;
  const int tid = threadIdx.x, ch = tid >> 6, lane = tid & 63;
  const int l31 = lane & 31, h5 = lane >> 5;
  const int n = bx*32 + l31;
  const int t0 = 2*ch, t1 = t0 + 1;

  f32x16 zero = {};
  f32x16 acc[2] = {zero, zero};
  const float* erow = emb + (size_t)n*kE + h5*8;
  #pragma unroll
  for (int c = 0; c < 6; ++c) {
    float4 a = *(const float4*)(erow + c*16);
    float4 b = *(const float4*)(erow + c*16 + 4);
    f16x8 v;
    v[0]=(f16)a.x; v[1]=(f16)a.y; v[2]=(f16)a.z; v[3]=(f16)a.w;
    v[4]=(f16)b.x; v[5]=(f16)b.y; v[6]=(f16)b.z; v[7]=(f16)b.w;
    acc[0] = MFMA_(gfrag(fW0, c*4+t0, lane), v, acc[0], 0, 0, 0);
    acc[1] = MFMA_(gfrag(fW0, c*4+t1, lane), v, acc[1], 0, 0, 0);
  }

  f16x8 hq[2][2];
  #pragma unroll
  for (int ti = 0; ti < 2; ++ti) {
    int t = 2*ch + ti;
    #pragma unroll
    for (int q = 0; q < 4; ++q) {
      float4 b4 = *(const float4*)(b0 + t*32 + q*8 + h5*4);
      const float* bp = (const float*)&b4;
      #pragma unroll
      for (int e = 0; e < 4; ++e) {
        float z = acc[ti][q*4+e] + bp[e];
        hq[ti][q>>1][(q&1)*4+e] = (f16)fmaxf(z, SLOPE_*z);
      }
    }
  }
  #pragma unroll
  for (int ti = 0; ti < 2; ++ti)
    #pragma unroll
    for (int hf = 0; hf < 2; ++hf)
      *(f16x8*)&act[4*ch + 2*ti + hf][lane*8] = hq[ti][hf];
  __syncthreads();                             // B1: L0 acts visible

  // L1
  acc[0] = zero; acc[1] = zero;
  #pragma unroll
  for (int c = 0; c < 8; ++c) {
    f16x8 bP = ((c >> 2) == ch) ? hq[(c>>1)&1][c&1]
                                : *(const f16x8*)&act[c][lane*8];
    acc[0] = MFMA_(gfrag(fW1, c*4+t0, lane), bP, acc[0], 0, 0, 0);
    acc[1] = MFMA_(gfrag(fW1, c*4+t1, lane), bP, acc[1], 0, 0, 0);
  }
  __syncthreads();                             // B2: L1 reads done
  #pragma unroll
  for (int ti = 0; ti < 2; ++ti) {
    int t = 2*ch + ti;
    #pragma unroll
    for (int q = 0; q < 4; ++q) {
      float4 b4 = *(const float4*)(b1 + t*32 + q*8 + h5*4);
      const float* bp = (const float*)&b4;
      #pragma unroll
      for (int e = 0; e < 4; ++e) {
        float z = acc[ti][q*4+e] + bp[e];
        hq[ti][q>>1][(q&1)*4+e] = (f16)fmaxf(z, SLOPE_*z);
      }
    }
  }
  #pragma unroll
  for (int ti = 0; ti < 2; ++ti)
    #pragma unroll
    for (int hf = 0; hf < 2; ++hf)
      *(f16x8*)&act[4*ch + 2*ti + hf][lane*8] = hq[ti][hf];
  __syncthreads();                             // B3: L1 acts visible

  // Lf (no activation)
  acc[0] = zero; acc[1] = zero;
  #pragma unroll
  for (int c = 0; c < 8; ++c) {
    f16x8 bP = ((c >> 2) == ch) ? hq[(c>>1)&1][c&1]
                                : *(const f16x8*)&act[c][lane*8];
    acc[0] = MFMA_(gfrag(fWf, c*4+t0, lane), bP, acc[0], 0, 0, 0);
    acc[1] = MFMA_(gfrag(fWf, c*4+t1, lane), bP, acc[1], 0, 0, 0);
  }
  #pragma unroll
  for (int ti = 0; ti < 2; ++ti) {
    int t = 2*ch + ti;
    #pragma unroll
    for (int q = 0; q < 4; ++q) {
      float4 b4 = *(const float4*)(bf + t*32 + q*8 + h5*4);
      const float* bp = (const float*)&b4;
      #pragma unroll
      for (int e = 0; e < 4; ++e)
        hq[ti][q>>1][(q&1)*4+e] = (f16)(acc[ti][q*4+e] + bp[e]);
    }
  }
  // store own chunks, block-chunked frag layout (coalesced per 32 lanes)
  #pragma unroll
  for (int ti = 0; ti < 2; ++ti)
    #pragma unroll
    for (int hf = 0; hf < 2; ++hf) {
      int c = 4*ch + 2*ti + hf;
      *(f16x8*)(out + (size_t)bx*4096 + (c*2 + h5)*256 + l31*8) = hq[ti][hf];
    }
}

// ==== g_mlp fwd + JVP: col-split waves, 32-row blocks, global weights =======
__global__ __launch_bounds__(128, 3) void g_kernel(
    const float* __restrict__ x, const f16* __restrict__ embh,
    const f16* __restrict__ W0img, const f16* __restrict__ W1img,
    const f16* __restrict__ W2img,
    const float* __restrict__ w144buf,
    const float* __restrict__ gb0, const float* __restrict__ gb1,
    const float* __restrict__ gb2, const float* __restrict__ gWf,
    const float* __restrict__ gbf,
    float* __restrict__ resid, float* __restrict__ logdet)
{
  __shared__ f16 actP[8][512], actT[8][512];   // 16 KB exchange
  __shared__ float pbuf[32], tbuf[32];
  const int d = blockIdx.y, bx = blockIdx.x;
  const int tid = threadIdx.x, ch = tid >> 6, lane = tid & 63;
  const int l31 = lane & 31, h5 = lane >> 5;
  const int n = bx*32 + l31;
  const int b = n / kTM, tt = n - b*kTM;
  const int t0 = 2*ch, t1 = t0 + 1;

  const f16* W0d = W0img + d*36*512;
  const f16* W1d = W1img + d*32*512;
  const f16* W2d = W2img + d*32*512;

  // L0 B-frags: embh (block-chunked, coalesced) + yy from x + xx scalar
  const f16* erow = embh + (size_t)bx*4096 + h5*256 + l31*8;
  f16x8 embF[8];
  #pragma unroll
  for (int c = 0; c < 8; ++c) embF[c] = *(const f16x8*)(erow + c*512);
  const float* xp = x + ((size_t)b*kT + tt + h5)*kD;
  float4 xa = *(const float4*)xp;
  float4 xb = *(const float4*)(xp + 4);
  f16x8 f8;
  f8[0]=(f16)xa.x; f8[1]=(f16)xa.y; f8[2]=(f16)xa.z; f8[3]=(f16)xa.w;
  f8[4]=(f16)xb.x; f8[5]=(f16)xb.y; f8[6]=(f16)xb.z; f8[7]=(f16)xb.w;
  const float xxv = x[((size_t)b*kT + tt + 2)*kD + d];

  f32x16 zero = {};
  f32x16 aP[2] = {zero, zero};
  #pragma unroll
  for (int c = 0; c < 8; ++c) {
    aP[0] = MFMA_(gfrag(W0d, c*4+t0, lane), embF[c], aP[0], 0, 0, 0);
    aP[1] = MFMA_(gfrag(W0d, c*4+t1, lane), embF[c], aP[1], 0, 0, 0);
  }
  aP[0] = MFMA_(gfrag(W0d, 32+t0, lane), f8, aP[0], 0, 0, 0);
  aP[1] = MFMA_(gfrag(W0d, 32+t1, lane), f8, aP[1], 0, 0, 0);

  f16x8 hqP[2][2], hqT[2][2];
  #pragma unroll
  for (int ti = 0; ti < 2; ++ti) {
    int t = 2*ch + ti;
    #pragma unroll
    for (int q = 0; q < 4; ++q) {
      float4 w4 = *(const float4*)(w144buf + d*kH + t*32 + q*8 + h5*4);
      float4 b4 = *(const float4*)(gb0 + d*kH + t*32 + q*8 + h5*4);
      const float* wp = (const float*)&w4;
      const float* bp = (const float*)&b4;
      #pragma unroll
      for (int e = 0; e < 4; ++e) {
        float z = aP[ti][q*4+e] + xxv*wp[e] + bp[e];
        float m = (z >= 0.f) ? 1.f : SLOPE_;
        hqP[ti][q>>1][(q&1)*4+e] = (f16)(z*m);
        hqT[ti][q>>1][(q&1)*4+e] = (f16)(wp[e]*m);
      }
    }
  }
  #pragma unroll
  for (int ti = 0; ti < 2; ++ti)
    #pragma unroll
    for (int hf = 0; hf < 2; ++hf) {
      int c = 4*ch + 2*ti + hf;
      *(f16x8*)&actP[c][lane*8] = hqP[ti][hf];
      *(f16x8*)&actT[c][lane*8] = hqT[ti][hf];
    }
  __syncthreads();                             // B1

  // ---- L1
  f32x16 cP[2] = {zero, zero}, cT[2] = {zero, zero};
  #pragma unroll
  for (int c = 0; c < 8; ++c) {
    f16x8 bP, bT;
    if ((c >> 2) == ch) { bP = hqP[(c>>1)&1][c&1]; bT = hqT[(c>>1)&1][c&1]; }
    else { bP = *(const f16x8*)&actP[c][lane*8];
           bT = *(const f16x8*)&actT[c][lane*8]; }
    f16x8 a0 = gfrag(W1d, c*4+t0, lane);
    f16x8 a1 = gfrag(W1d, c*4+t1, lane);
    cP[0] = MFMA_(a0, bP, cP[0], 0, 0, 0);
    cT[0] = MFMA_(a0, bT, cT[0], 0, 0, 0);
    cP[1] = MFMA_(a1, bP, cP[1], 0, 0, 0);
    cT[1] = MFMA_(a1, bT, cT[1], 0, 0, 0);
  }
  __syncthreads();                             // B2: L1 reads done
  #pragma unroll
  for (int ti = 0; ti < 2; ++ti) {
    int t = 2*ch + ti;
    #pragma unroll
    for (int q = 0; q < 4; ++q) {
      float4 b4 = *(const float4*)(gb1 + d*kH + t*32 + q*8 + h5*4);
      const float* bp = (const float*)&b4;
      #pragma unroll
      for (int e = 0; e < 4; ++e) {
        float z = cP[ti][q*4+e] + bp[e];
        float tv = cT[ti][q*4+e];
        float m = (z >= 0.f) ? 1.f : SLOPE_;
        hqP[ti][q>>1][(q&1)*4+e] = (f16)(z*m);
        hqT[ti][q>>1][(q&1)*4+e] = (f16)(tv*m);
      }
    }
  }
  #pragma unroll
  for (int ti = 0; ti < 2; ++ti)
    #pragma unroll
    for (int hf = 0; hf < 2; ++hf) {
      int c = 4*ch + 2*ti + hf;
      *(f16x8*)&actP[c][lane*8] = hqP[ti][hf];
      *(f16x8*)&actT[c][lane*8] = hqT[ti][hf];
    }
  __syncthreads();                             // B3

  // ---- L2
  cP[0] = zero; cP[1] = zero; cT[0] = zero; cT[1] = zero;
  #pragma unroll
  for (int c = 0; c < 8; ++c) {
    f16x8 bP, bT;
    if ((c >> 2) == ch) { bP = hqP[(c>>1)&1][c&1]; bT = hqT[(c>>1)&1][c&1]; }
    else { bP = *(const f16x8*)&actP[c][lane*8];
           bT = *(const f16x8*)&actT[c][lane*8]; }
    f16x8 a0 = gfrag(W2d, c*4+t0, lane);
    f16x8 a1 = gfrag(W2d, c*4+t1, lane);
    cP[0] = MFMA_(a0, bP, cP[0], 0, 0, 0);
    cT[0] = MFMA_(a0, bT, cT[0], 0, 0, 0);
    cP[1] = MFMA_(a1, bP, cP[1], 0, 0, 0);
    cT[1] = MFMA_(a1, bT, cT[1], 0, 0, 0);
  }

  // ---- final epilogue + partial dot with wf over this wave's 2 tiles
  float p = 0.f, tp = 0.f;
  #pragma unroll
  for (int ti = 0; ti < 2; ++ti) {
    int t = 2*ch + ti;
    #pragma unroll
    for (int q = 0; q < 4; ++q) {
      float4 b4 = *(const float4*)(gb2 + d*kH + t*32 + q*8 + h5*4);
      float4 w4 = *(const float4*)(gWf + d*kH + t*32 + q*8 + h5*4);
      const float* bp = (const float*)&b4;
      const float* wp = (const float*)&w4;
      #pragma unroll
      for (int e = 0; e < 4; ++e) {
        float z = cP[ti][q*4+e] + bp[e];
        float tv = cT[ti][q*4+e];
        float zl = fmaxf(z, SLOPE_*z);
        float tl = (z >= 0.f) ? tv : SLOPE_*tv;
        p  = fmaf(zl, wp[e], p);
        tp = fmaf(tl, wp[e], tp);
      }
    }
  }
  p  += __shfl_xor(p, 32, 64);
  tp += __shfl_xor(tp, 32, 64);
  if (ch == 1 && h5 == 0) { pbuf[l31] = p; tbuf[l31] = tp; }
  __syncthreads();                             // B4
  if (ch == 0 && h5 == 0) {
    float pf = p + pbuf[l31];
    float tf = tp + tbuf[l31];
    resid[(size_t)n*kD + d] = pf + gbf[d];
    float llog = logf(fabsf(tf));
    int bfirst = (bx*32) / kTM;
    float s0 = (b == bfirst) ? llog : 0.f;
    float s1 = llog - s0;
    #pragma unroll
    for (int off = 16; off > 0; off >>= 1) {
      s0 += __shfl_down(s0, off, 32);
      s1 += __shfl_down(s1, off, 32);
    }
    if (l31 == 0) {
      atomicAdd(&logdet[bfirst], s0);
      if (s1 != 0.f) atomicAdd(&logdet[bfirst + 1], s1);
    }
  }
}

extern "C" void kernel_launch(void* const* d_in, const int* in_sizes, int n_in,
                              void* d_out, int out_size, void* d_ws, size_t ws_size,
                              hipStream_t stream) {
  const float* x    = (const float*)d_in[0];
  const float* emb  = (const float*)d_in[1];
  const float* fcW0 = (const float*)d_in[2];
  const float* fcb0 = (const float*)d_in[3];
  const float* fcW1 = (const float*)d_in[4];
  const float* fcb1 = (const float*)d_in[5];
  const float* fcWf = (const float*)d_in[6];
  const float* fcbf = (const float*)d_in[7];
  const float* gW0  = (const float*)d_in[8];
  const float* gb0  = (const float*)d_in[9];
  const float* gW1  = (const float*)d_in[10];
  const float* gb1  = (const float*)d_in[11];
  const float* gW2  = (const float*)d_in[12];
  const float* gb2  = (const float*)d_in[13];
  const float* gWf  = (const float*)d_in[14];
  const float* gbf  = (const float*)d_in[15];
  float* out = (float*)d_out;
  float* logdet = out + (size_t)kN * kD;

  char* ws = (char*)d_ws;
  f16*   embh    = (f16*)ws;    ws += (size_t)kN*kH*2;
  f16*   W0img   = (f16*)ws;    ws += (size_t)kD*36*512*2;
  f16*   W1img   = (f16*)ws;    ws += (size_t)kD*32*512*2;
  f16*   W2img   = (f16*)ws;    ws += (size_t)kD*32*512*2;
  f16*   fW0img  = (f16*)ws;    ws += (size_t)24*512*2;
  f16*   fW1img  = (f16*)ws;    ws += (size_t)32*512*2;
  f16*   fWfimg  = (f16*)ws;    ws += (size_t)32*512*2;
  float* w144buf = (float*)ws;

  cvt_kernel<<<256, 256, 0, stream>>>(gW0, gW1, gW2, fcW0, fcW1, fcWf,
                                      W0img, W1img, W2img,
                                      fW0img, fW1img, fWfimg,
                                      w144buf, logdet);
  fc_kernel<<<kN/32, 128, 0, stream>>>(emb, fW0img, fW1img, fWfimg,
                                       fcb0, fcb1, fcbf, embh);
  g_kernel<<<dim3(kN/32, kD), 128, 0, stream>>>(
      x, embh, W0img, W1img, W2img, w144buf,
      gb0, gb1, gb2, gWf, gbf, out, logdet);
}